// Round 5
// baseline (104.661 us; speedup 1.0000x reference)
//
#include <hip/hip_runtime.h>

#define BATCH     256
#define INPUT_DIM 4096
#define SOMA      2048
#define BRANCHES  16
#define NDEND     32768
#define SAMPLE    32

#define THREADS   1024
#define B_T       8                      // batch rows per tile (8 bf16 per b128)
#define NTILES    4                      // 32 batch rows per block
#define TILE_B    (INPUT_DIM * B_T * 2)  // bytes per LDS buffer = 64 KiB

typedef unsigned int u32;
typedef __attribute__((address_space(1))) const u32 gu32;
typedef __attribute__((address_space(3))) u32 lu32;

__device__ __forceinline__ void async_load16(const void* g, void* l) {
    __builtin_amdgcn_global_load_lds((const gu32*)g, (lu32*)l, 16, 0, 0);
}

__device__ __forceinline__ u32 bf16rne(float f) {   // round-to-nearest-even bf16
    u32 u = __float_as_uint(f);
    return (u + 0x7FFFu + ((u >> 16) & 1u)) >> 16;
}

// ---- pack x[256][4096] f32 -> xB[32 btile][4096 i][8 bb] bf16 (tile = LDS image) ----
#define TT 64
__global__ __launch_bounds__(256)
void pack_kernel(const float* __restrict__ x, u32* __restrict__ xB)
{
    __shared__ float ts[TT * (TT + 1)];             // ts[i_loc*65 + b_loc]
    const int j  = threadIdx.x;
    const int tx = j & 63;
    const int ty = j >> 6;                          // 0..3
    const int gi = blockIdx.x * TT;
    const int gb = blockIdx.y * TT;

    #pragma unroll
    for (int r = 0; r < 16; ++r) {                  // read x coalesced along i
        const int b = ty + 4 * r;
        ts[tx * (TT + 1) + b] = x[(size_t)(gb + b) * INPUT_DIM + gi + tx];
    }
    __syncthreads();

    #pragma unroll
    for (int rep = 0; rep < 2; ++rep) {             // 512 items of 16B
        const int idx   = rep * 256 + j;
        const int i_loc = idx & 63;                 // consecutive lanes -> coalesced store
        const int bg    = idx >> 6;                 // batch group 0..7
        const float* s  = &ts[i_loc * (TT + 1) + bg * 8];
        uint4 q;
        q.x = bf16rne(s[0]) | (bf16rne(s[1]) << 16);
        q.y = bf16rne(s[2]) | (bf16rne(s[3]) << 16);
        q.z = bf16rne(s[4]) | (bf16rne(s[5]) << 16);
        q.w = bf16rne(s[6]) | (bf16rne(s[7]) << 16);
        ((uint4*)xB)[(size_t)(gb / 8 + bg) * INPUT_DIM + gi + i_loc] = q;
    }
}

// ---------------- main fused kernel ----------------
__global__ __launch_bounds__(THREADS, 4)
void dendrite_kernel(const char* __restrict__ xB,    // tiled bf16 image
                     const int*   __restrict__ didx,
                     const float* __restrict__ sw,
                     const float* __restrict__ sb,
                     const float* __restrict__ cw,
                     const float* __restrict__ somab,
                     float* __restrict__ soma_out,   // [BATCH][SOMA]
                     float* __restrict__ dend_out)   // [BATCH][NDEND]
{
    extern __shared__ char xs[];                    // 2 x 64 KiB

    const int t  = threadIdx.x;
    const int dc = blockIdx.x;                      // dendrite chunk (32)
    const int bs = blockIdx.y;                      // batch super-tile (8)
    const int d  = dc * THREADS + t;

    // ---- idx/w once into registers ----
    uint  off[SAMPLE / 2];
    float w[SAMPLE];
    {
        const int4*   ip = (const int4*)  (didx + (size_t)d * SAMPLE);
        const float4* wp = (const float4*)(sw   + (size_t)d * SAMPLE);
        #pragma unroll
        for (int g = 0; g < SAMPLE / 4; ++g) {
            const int4   iv = ip[g];
            const float4 wv = wp[g];
            off[2*g]   = ((uint)iv.x << 4) | ((uint)iv.y << 20);   // byte off = i*16
            off[2*g+1] = ((uint)iv.z << 4) | ((uint)iv.w << 20);
            w[4*g] = wv.x; w[4*g+1] = wv.y; w[4*g+2] = wv.z; w[4*g+3] = wv.w;
        }
    }
    const float bias = sb[d];
    const float cwv  = cw[d];
    const int   n    = d >> 4;
    const float sbi  = somab[n];

    // ---- stage tile 0: contiguous 64KB, perfectly coalesced, zero VGPR ----
    const char* tbase0 = xB + (size_t)(bs * NTILES) * TILE_B;
    #pragma unroll
    for (int r = 0; r < TILE_B / 16 / THREADS; ++r) {    // 4 per thread
        const int o = (r * THREADS + t) * 16;
        async_load16(tbase0 + o, xs + o);
    }

    for (int k = 0; k < NTILES; ++k) {
        const int b0 = bs * (B_T * NTILES) + k * B_T;
        const char* buf = xs + (k & 1) * TILE_B;

        asm volatile("s_waitcnt vmcnt(0)" ::: "memory");  // stage(k) landed
        __syncthreads();                                  // buf ready; prev readers done

        if (k + 1 < NTILES) {                             // async stage(k+1)
            const char* tb = xB + (size_t)(bs * NTILES + k + 1) * TILE_B;
            char* nbuf = xs + ((k + 1) & 1) * TILE_B;
            #pragma unroll
            for (int r = 0; r < TILE_B / 16 / THREADS; ++r) {
                const int o = (r * THREADS + t) * 16;
                async_load16(tb + o, nbuf + o);
            }
        }

        // ---- gather + unpack + FMA ----
        float acc[B_T] = {0.f,0.f,0.f,0.f,0.f,0.f,0.f,0.f};
        #pragma unroll
        for (int g = 0; g < SAMPLE / 2; ++g) {
            const uint pr = off[g];
            const uint4 q0 = *(const uint4*)(buf + (pr & 0xFFFFu));
            const uint4 q1 = *(const uint4*)(buf + (pr >> 16));
            const float w0 = w[2*g], w1 = w[2*g+1];
            acc[0] += __uint_as_float(q0.x << 16)          * w0;
            acc[1] += __uint_as_float(q0.x & 0xFFFF0000u)  * w0;
            acc[2] += __uint_as_float(q0.y << 16)          * w0;
            acc[3] += __uint_as_float(q0.y & 0xFFFF0000u)  * w0;
            acc[4] += __uint_as_float(q0.z << 16)          * w0;
            acc[5] += __uint_as_float(q0.z & 0xFFFF0000u)  * w0;
            acc[6] += __uint_as_float(q0.w << 16)          * w0;
            acc[7] += __uint_as_float(q0.w & 0xFFFF0000u)  * w0;
            acc[0] += __uint_as_float(q1.x << 16)          * w1;
            acc[1] += __uint_as_float(q1.x & 0xFFFF0000u)  * w1;
            acc[2] += __uint_as_float(q1.y << 16)          * w1;
            acc[3] += __uint_as_float(q1.y & 0xFFFF0000u)  * w1;
            acc[4] += __uint_as_float(q1.z << 16)          * w1;
            acc[5] += __uint_as_float(q1.z & 0xFFFF0000u)  * w1;
            acc[6] += __uint_as_float(q1.w << 16)          * w1;
            acc[7] += __uint_as_float(q1.w & 0xFFFF0000u)  * w1;
        }

        // ---- epilogue ----
        float part[B_T];
        #pragma unroll
        for (int bb = 0; bb < B_T; ++bb) {
            const float pre = acc[bb] + bias;
            const float act = (pre >= 0.f) ? pre : 0.1f * pre;
            dend_out[(size_t)(b0 + bb) * NDEND + d] = act;    // coalesced
            part[bb] = act * cwv;
        }
        #pragma unroll
        for (int m = 1; m < BRANCHES; m <<= 1) {
            #pragma unroll
            for (int bb = 0; bb < B_T; ++bb)
                part[bb] += __shfl_xor(part[bb], m);
        }
        if ((t & (BRANCHES - 1)) == 0) {
            #pragma unroll
            for (int bb = 0; bb < B_T; ++bb) {
                const float pre = part[bb] + sbi;
                soma_out[(size_t)(b0 + bb) * SOMA + n] = (pre >= 0.f) ? pre : 0.1f * pre;
            }
        }
    }
}

extern "C" void kernel_launch(void* const* d_in, const int* in_sizes, int n_in,
                              void* d_out, int out_size, void* d_ws, size_t ws_size,
                              hipStream_t stream) {
    const float* x     = (const float*)d_in[0];
    const int*   didx  = (const int*)  d_in[1];
    const float* sw    = (const float*)d_in[2];
    const float* sb    = (const float*)d_in[3];
    const float* cw    = (const float*)d_in[4];
    const float* somab = (const float*)d_in[5];

    float* soma_out = (float*)d_out;                     // [256][2048]
    float* dend_out = soma_out + (size_t)BATCH * SOMA;   // [256][32768]
    u32*   xB       = (u32*)d_ws;                        // 2 MiB tiled bf16 image

    static bool attr_set = false;
    if (!attr_set) {
        hipFuncSetAttribute((const void*)dendrite_kernel,
                            hipFuncAttributeMaxDynamicSharedMemorySize, 2 * TILE_B);
        attr_set = true;
    }

    dim3 pgrid(INPUT_DIM / TT, BATCH / TT);              // (64, 4)
    pack_kernel<<<pgrid, 256, 0, stream>>>(x, xB);

    dim3 grid(NDEND / THREADS, BATCH / (B_T * NTILES));  // (32, 8) = 256 blocks
    dendrite_kernel<<<grid, THREADS, 2 * TILE_B, stream>>>(
        (const char*)xB, didx, sw, sb, cw, somab, soma_out, dend_out);
}

// Round 6
// 78.951 us; speedup vs baseline: 1.3256x; 1.3256x over previous
//
#include <hip/hip_runtime.h>

#define BATCH     256
#define INPUT_DIM 4096
#define SOMA      2048
#define BRANCHES  16
#define NDEND     32768
#define SAMPLE    32

#define THREADS   512
#define B_T       8                      // batch rows per block (8 bf16 per b128)

typedef unsigned int u32;

__device__ __forceinline__ u32 bf16rne(float f) {   // round-to-nearest-even bf16
    u32 u = __float_as_uint(f);
    return (u + 0x7FFFu + ((u >> 16) & 1u)) >> 16;  // low 16 bits hold bf16
}

__global__ __launch_bounds__(THREADS, 4)            // <=128 VGPR, 2 blocks/CU
void dendrite_kernel(const float* __restrict__ x,
                     const int*   __restrict__ didx,
                     const float* __restrict__ sw,
                     const float* __restrict__ sb,
                     const float* __restrict__ cw,
                     const float* __restrict__ somab,
                     float* __restrict__ soma_out,   // [BATCH][SOMA]
                     float* __restrict__ dend_out)   // [BATCH][NDEND]
{
    // xs[i] = 8 batch rows of x[:,i], bf16-packed into 16B.  64 KiB exactly.
    __shared__ uint4 xs[INPUT_DIM];

    const int t  = threadIdx.x;
    const int bs = blockIdx.x;                      // batch slice (8)  -> XCD = bs
    const int dc = blockIdx.y;                      // dendrite chunk (64)
    const int d  = dc * THREADS + t;                // this thread's dendrite
    const int b0 = bs * B_T;

    // ---- idx/w once into registers (consumed after the barrier) ----
    uint  off[SAMPLE / 2];
    float w[SAMPLE];
    {
        const int4*   ip = (const int4*)  (didx + (size_t)d * SAMPLE);
        const float4* wp = (const float4*)(sw   + (size_t)d * SAMPLE);
        #pragma unroll
        for (int g = 0; g < SAMPLE / 4; ++g) {
            const int4   iv = ip[g];
            const float4 wv = wp[g];
            off[2*g]   = ((uint)iv.x << 4) | ((uint)iv.y << 20);  // byte off = i*16
            off[2*g+1] = ((uint)iv.z << 4) | ((uint)iv.w << 20);
            w[4*g] = wv.x; w[4*g+1] = wv.y; w[4*g+2] = wv.z; w[4*g+3] = wv.w;
        }
    }
    const float bias = sb[d];
    const float cwv  = cw[d];
    const int   n    = d >> 4;
    const float sbi  = somab[n];

    // ---- stage: 8 i-positions/thread; scalar coalesced reads, b128 write ----
    const float* xb = x + (size_t)b0 * INPUT_DIM;
    #pragma unroll
    for (int r = 0; r < INPUT_DIM / THREADS; ++r) {  // 8
        const int i = r * THREADS + t;
        u32 u0 = bf16rne(xb[i]);
        u32 u1 = bf16rne(xb[    INPUT_DIM + i]);
        u32 u2 = bf16rne(xb[2 * INPUT_DIM + i]);
        u32 u3 = bf16rne(xb[3 * INPUT_DIM + i]);
        u32 u4 = bf16rne(xb[4 * INPUT_DIM + i]);
        u32 u5 = bf16rne(xb[5 * INPUT_DIM + i]);
        u32 u6 = bf16rne(xb[6 * INPUT_DIM + i]);
        u32 u7 = bf16rne(xb[7 * INPUT_DIM + i]);
        uint4 q;
        q.x = u0 | (u1 << 16);
        q.y = u2 | (u3 << 16);
        q.z = u4 | (u5 << 16);
        q.w = u6 | (u7 << 16);
        xs[i] = q;                                   // bank = (i*4)%32: conflict-free
    }
    __syncthreads();

    // ---- gather + unpack + FMA (regs + LDS only) ----
    const char* buf = (const char*)xs;
    float acc[B_T] = {0.f,0.f,0.f,0.f,0.f,0.f,0.f,0.f};
    #pragma unroll
    for (int g = 0; g < SAMPLE / 2; ++g) {
        const uint pr = off[g];
        const uint4 q0 = *(const uint4*)(buf + (pr & 0xFFFFu));
        const uint4 q1 = *(const uint4*)(buf + (pr >> 16));
        const float w0 = w[2*g], w1 = w[2*g+1];
        acc[0] += __uint_as_float(q0.x << 16)         * w0;
        acc[1] += __uint_as_float(q0.x & 0xFFFF0000u) * w0;
        acc[2] += __uint_as_float(q0.y << 16)         * w0;
        acc[3] += __uint_as_float(q0.y & 0xFFFF0000u) * w0;
        acc[4] += __uint_as_float(q0.z << 16)         * w0;
        acc[5] += __uint_as_float(q0.z & 0xFFFF0000u) * w0;
        acc[6] += __uint_as_float(q0.w << 16)         * w0;
        acc[7] += __uint_as_float(q0.w & 0xFFFF0000u) * w0;
        acc[0] += __uint_as_float(q1.x << 16)         * w1;
        acc[1] += __uint_as_float(q1.x & 0xFFFF0000u) * w1;
        acc[2] += __uint_as_float(q1.y << 16)         * w1;
        acc[3] += __uint_as_float(q1.y & 0xFFFF0000u) * w1;
        acc[4] += __uint_as_float(q1.z << 16)         * w1;
        acc[5] += __uint_as_float(q1.z & 0xFFFF0000u) * w1;
        acc[6] += __uint_as_float(q1.w << 16)         * w1;
        acc[7] += __uint_as_float(q1.w & 0xFFFF0000u) * w1;
    }

    // ---- epilogue: activation, dend store, soma reduce/store ----
    float part[B_T];
    #pragma unroll
    for (int bb = 0; bb < B_T; ++bb) {
        const float pre = acc[bb] + bias;
        const float act = (pre >= 0.f) ? pre : 0.1f * pre;
        dend_out[(size_t)(b0 + bb) * NDEND + d] = act;   // coalesced across lanes
        part[bb] = act * cwv;
    }
    #pragma unroll
    for (int m = 1; m < BRANCHES; m <<= 1) {
        #pragma unroll
        for (int bb = 0; bb < B_T; ++bb)
            part[bb] += __shfl_xor(part[bb], m);
    }
    if ((t & (BRANCHES - 1)) == 0) {
        #pragma unroll
        for (int bb = 0; bb < B_T; ++bb) {
            const float pre = part[bb] + sbi;
            soma_out[(size_t)(b0 + bb) * SOMA + n] = (pre >= 0.f) ? pre : 0.1f * pre;
        }
    }
}

extern "C" void kernel_launch(void* const* d_in, const int* in_sizes, int n_in,
                              void* d_out, int out_size, void* d_ws, size_t ws_size,
                              hipStream_t stream) {
    const float* x     = (const float*)d_in[0];
    const int*   didx  = (const int*)  d_in[1];
    const float* sw    = (const float*)d_in[2];
    const float* sb    = (const float*)d_in[3];
    const float* cw    = (const float*)d_in[4];
    const float* somab = (const float*)d_in[5];

    float* soma_out = (float*)d_out;                     // [256][2048]
    float* dend_out = soma_out + (size_t)BATCH * SOMA;   // [256][32768]

    // grid.x = batch slice so linear%8 == bs -> one XCD per batch slice
    dim3 grid(BATCH / B_T, NDEND / THREADS);             // (8, 64) wait -> (32, 64)? no: 256/8=32
    // BATCH/B_T = 32 batch slices of 8 rows; each block does one slice x 512 dendrites
    dendrite_kernel<<<grid, THREADS, 0, stream>>>(x, didx, sw, sb, cw, somab,
                                                  soma_out, dend_out);
}

// Round 7
// 62.830 us; speedup vs baseline: 1.6658x; 1.2566x over previous
//
#include <hip/hip_runtime.h>

#define BATCH     256
#define INPUT_DIM 4096
#define SOMA      2048
#define BRANCHES  16
#define NDEND     32768
#define SAMPLE    32

#define THREADS   512
#define B_T       8                      // batch rows per tile (8 bf16 per b128)
#define NBT       4                      // batch tiles per block -> 32 rows/block

typedef unsigned int u32;
typedef float f32x2 __attribute__((ext_vector_type(2)));

__device__ __forceinline__ u32 bf16rne(float f) {   // round-to-nearest-even bf16
    u32 u = __float_as_uint(f);
    return (u + 0x7FFFu + ((u >> 16) & 1u)) >> 16;  // low 16 bits hold bf16
}

__global__ __launch_bounds__(THREADS, 4)            // <=128 VGPR, 2 blocks/CU
void dendrite_kernel(const float* __restrict__ x,
                     const int*   __restrict__ didx,
                     const float* __restrict__ sw,
                     const float* __restrict__ sb,
                     const float* __restrict__ cw,
                     const float* __restrict__ somab,
                     float* __restrict__ soma_out,   // [BATCH][SOMA]
                     float* __restrict__ dend_out)   // [BATCH][NDEND]
{
    // xs[i] = 8 batch rows of x[:,i] bf16-packed into 16B.  64 KiB, single buffer.
    __shared__ uint4 xs[INPUT_DIM];

    const int t  = threadIdx.x;
    const int dc = blockIdx.x;   // dendrite chunk (64): XCD = dc%8 -> all bs co-XCD
    const int bs = blockIdx.y;   // batch super-tile (8)
    const int d  = dc * THREADS + t;                // this thread's dendrite, forever

    // ---- idx/w/bias/cable ONCE into registers ----
    uint  off[SAMPLE / 2];
    float w[SAMPLE];
    {
        const int4*   ip = (const int4*)  (didx + (size_t)d * SAMPLE);
        const float4* wp = (const float4*)(sw   + (size_t)d * SAMPLE);
        #pragma unroll
        for (int g = 0; g < SAMPLE / 4; ++g) {
            const int4   iv = ip[g];
            const float4 wv = wp[g];
            off[2*g]   = ((u32)iv.x << 4) | ((u32)iv.y << 20);  // byte off = i*16
            off[2*g+1] = ((u32)iv.z << 4) | ((u32)iv.w << 20);
            w[4*g] = wv.x; w[4*g+1] = wv.y; w[4*g+2] = wv.z; w[4*g+3] = wv.w;
        }
    }
    const float bias = sb[d];
    const float cwv  = cw[d];
    const int   n    = d >> 4;
    const float sbi  = somab[n];

    for (int k = 0; k < NBT; ++k) {
        const int b0 = bs * (B_T * NBT) + k * B_T;
        const float* xb = x + (size_t)b0 * INPUT_DIM;

        __syncthreads();                            // previous tile's readers done

        // ---- stage: 8 i/thread, scalar coalesced reads, conflict-free b128 write ----
        #pragma unroll
        for (int r = 0; r < INPUT_DIM / THREADS; ++r) {   // 8
            const int i = r * THREADS + t;
            u32 u0 = bf16rne(xb[i]);
            u32 u1 = bf16rne(xb[    INPUT_DIM + i]);
            u32 u2 = bf16rne(xb[2 * INPUT_DIM + i]);
            u32 u3 = bf16rne(xb[3 * INPUT_DIM + i]);
            u32 u4 = bf16rne(xb[4 * INPUT_DIM + i]);
            u32 u5 = bf16rne(xb[5 * INPUT_DIM + i]);
            u32 u6 = bf16rne(xb[6 * INPUT_DIM + i]);
            u32 u7 = bf16rne(xb[7 * INPUT_DIM + i]);
            uint4 q;
            q.x = u0 | (u1 << 16);
            q.y = u2 | (u3 << 16);
            q.z = u4 | (u5 << 16);
            q.w = u6 | (u7 << 16);
            xs[i] = q;
        }
        __syncthreads();                            // tile ready

        // ---- gather + unpack + packed FMA (regs + LDS only) ----
        const char* buf = (const char*)xs;
        f32x2 acc0 = {0.f,0.f}, acc1 = {0.f,0.f}, acc2 = {0.f,0.f}, acc3 = {0.f,0.f};
        #pragma unroll
        for (int g = 0; g < SAMPLE / 2; ++g) {
            const u32 pr = off[g];
            const uint4 q0 = *(const uint4*)(buf + (pr & 0xFFFFu));
            const uint4 q1 = *(const uint4*)(buf + (pr >> 16));
            const f32x2 w0 = {w[2*g],   w[2*g]};
            const f32x2 w1 = {w[2*g+1], w[2*g+1]};
            f32x2 v;
            v = (f32x2){__uint_as_float(q0.x << 16), __uint_as_float(q0.x & 0xFFFF0000u)};
            acc0 += v * w0;
            v = (f32x2){__uint_as_float(q0.y << 16), __uint_as_float(q0.y & 0xFFFF0000u)};
            acc1 += v * w0;
            v = (f32x2){__uint_as_float(q0.z << 16), __uint_as_float(q0.z & 0xFFFF0000u)};
            acc2 += v * w0;
            v = (f32x2){__uint_as_float(q0.w << 16), __uint_as_float(q0.w & 0xFFFF0000u)};
            acc3 += v * w0;
            v = (f32x2){__uint_as_float(q1.x << 16), __uint_as_float(q1.x & 0xFFFF0000u)};
            acc0 += v * w1;
            v = (f32x2){__uint_as_float(q1.y << 16), __uint_as_float(q1.y & 0xFFFF0000u)};
            acc1 += v * w1;
            v = (f32x2){__uint_as_float(q1.z << 16), __uint_as_float(q1.z & 0xFFFF0000u)};
            acc2 += v * w1;
            v = (f32x2){__uint_as_float(q1.w << 16), __uint_as_float(q1.w & 0xFFFF0000u)};
            acc3 += v * w1;
        }

        // ---- epilogue: activation, dend store, soma reduce/store ----
        const float a[B_T] = {acc0.x, acc0.y, acc1.x, acc1.y,
                              acc2.x, acc2.y, acc3.x, acc3.y};
        float part[B_T];
        #pragma unroll
        for (int bb = 0; bb < B_T; ++bb) {
            const float pre = a[bb] + bias;
            const float act = (pre >= 0.f) ? pre : 0.1f * pre;
            dend_out[(size_t)(b0 + bb) * NDEND + d] = act;   // coalesced
            part[bb] = act * cwv;
        }
        #pragma unroll
        for (int m = 1; m < BRANCHES; m <<= 1) {
            #pragma unroll
            for (int bb = 0; bb < B_T; ++bb)
                part[bb] += __shfl_xor(part[bb], m);
        }
        if ((t & (BRANCHES - 1)) == 0) {
            #pragma unroll
            for (int bb = 0; bb < B_T; ++bb) {
                const float pre = part[bb] + sbi;
                soma_out[(size_t)(b0 + bb) * SOMA + n] = (pre >= 0.f) ? pre : 0.1f * pre;
            }
        }
    }
}

extern "C" void kernel_launch(void* const* d_in, const int* in_sizes, int n_in,
                              void* d_out, int out_size, void* d_ws, size_t ws_size,
                              hipStream_t stream) {
    const float* x     = (const float*)d_in[0];
    const int*   didx  = (const int*)  d_in[1];
    const float* sw    = (const float*)d_in[2];
    const float* sb    = (const float*)d_in[3];
    const float* cw    = (const float*)d_in[4];
    const float* somab = (const float*)d_in[5];

    float* soma_out = (float*)d_out;                     // [256][2048]
    float* dend_out = soma_out + (size_t)BATCH * SOMA;   // [256][32768]

    // dc fastest-varying: XCD = dc%8, the 8 bs-blocks of chunk dc share its
    // idx/w via that XCD's L2 (concurrent residency: 512 blocks = 2/CU).
    dim3 grid(NDEND / THREADS, BATCH / (B_T * NBT));     // (64, 8)
    dendrite_kernel<<<grid, THREADS, 0, stream>>>(x, didx, sw, sb, cw, somab,
                                                  soma_out, dend_out);
}

// Round 8
// 44.967 us; speedup vs baseline: 2.3275x; 1.3973x over previous
//
#include <hip/hip_runtime.h>

#define BATCH     256
#define INPUT_DIM 4096
#define SOMA      2048
#define BRANCHES  16
#define NDEND     32768
#define SAMPLE    32

#define THREADS   512
#define B_T       8                      // batch rows per tile (8 bf16 per b128)
#define NBT       4                      // batch tiles per block -> 32 rows/block

typedef unsigned int u32;
typedef float f32x2 __attribute__((ext_vector_type(2)));

__device__ __forceinline__ u32 bf16rne(float f) {   // round-to-nearest-even bf16
    u32 u = __float_as_uint(f);
    return (u + 0x7FFFu + ((u >> 16) & 1u)) >> 16;  // low 16 bits hold bf16
}

// ---- pack x[256][4096] f32 -> xP[32 btile][4096 i][8 bb] bf16 (LDS image) ----
#define TT 64
__global__ __launch_bounds__(256)
void pack_kernel(const float* __restrict__ x, u32* __restrict__ xP)
{
    __shared__ float ts[TT * (TT + 1)];             // ts[i_loc*65 + b_loc]
    const int j  = threadIdx.x;
    const int tx = j & 63;
    const int ty = j >> 6;                          // 0..3
    const int gi = blockIdx.x * TT;
    const int gb = blockIdx.y * TT;

    #pragma unroll
    for (int r = 0; r < 16; ++r) {                  // read x coalesced along i
        const int b = ty + 4 * r;
        ts[tx * (TT + 1) + b] = x[(size_t)(gb + b) * INPUT_DIM + gi + tx];
    }
    __syncthreads();

    #pragma unroll
    for (int rep = 0; rep < 2; ++rep) {             // 512 items of 16B
        const int idx   = rep * 256 + j;
        const int i_loc = idx & 63;                 // consecutive lanes -> coalesced
        const int bg    = idx >> 6;                 // batch group 0..7
        const float* s  = &ts[i_loc * (TT + 1) + bg * 8];
        uint4 q;
        q.x = bf16rne(s[0]) | (bf16rne(s[1]) << 16);
        q.y = bf16rne(s[2]) | (bf16rne(s[3]) << 16);
        q.z = bf16rne(s[4]) | (bf16rne(s[5]) << 16);
        q.w = bf16rne(s[6]) | (bf16rne(s[7]) << 16);
        ((uint4*)xP)[(size_t)(gb / 8 + bg) * INPUT_DIM + gi + i_loc] = q;
    }
}

// ---------------- main fused kernel ----------------
__global__ __launch_bounds__(THREADS, 4)            // <=128 VGPR, 2 blocks/CU
void dendrite_kernel(const uint4* __restrict__ xP,  // [32][4096][8bb] bf16
                     const int*   __restrict__ didx,
                     const float* __restrict__ sw,
                     const float* __restrict__ sb,
                     const float* __restrict__ cw,
                     const float* __restrict__ somab,
                     float* __restrict__ soma_out,   // [BATCH][SOMA]
                     float* __restrict__ dend_out)   // [BATCH][NDEND]
{
    __shared__ uint4 xs[INPUT_DIM];                 // 64 KiB, single buffer

    const int t  = threadIdx.x;
    const int dc = blockIdx.x;   // dendrite chunk (64): XCD = dc%8 -> all bs co-XCD
    const int bs = blockIdx.y;   // batch super-tile (8)
    const int d  = dc * THREADS + t;                // this thread's dendrite, forever

    // ---- idx/w/bias/cable ONCE into registers ----
    uint  off[SAMPLE / 2];
    float w[SAMPLE];
    {
        const int4*   ip = (const int4*)  (didx + (size_t)d * SAMPLE);
        const float4* wp = (const float4*)(sw   + (size_t)d * SAMPLE);
        #pragma unroll
        for (int g = 0; g < SAMPLE / 4; ++g) {
            const int4   iv = ip[g];
            const float4 wv = wp[g];
            off[2*g]   = ((u32)iv.x << 4) | ((u32)iv.y << 20);  // byte off = i*16
            off[2*g+1] = ((u32)iv.z << 4) | ((u32)iv.w << 20);
            w[4*g] = wv.x; w[4*g+1] = wv.y; w[4*g+2] = wv.z; w[4*g+3] = wv.w;
        }
    }
    const float bias = sb[d];
    const float cwv  = cw[d];
    const int   n    = d >> 4;
    const float sbi  = somab[n];

    for (int k = 0; k < NBT; ++k) {
        const int b0 = bs * (B_T * NBT) + k * B_T;
        const uint4* tb = xP + (size_t)(bs * NBT + k) * INPUT_DIM;

        __syncthreads();                            // previous tile's readers done
        // ---- stage: 8 x uint4 coalesced loads -> conflict-free b128 writes ----
        #pragma unroll
        for (int r = 0; r < INPUT_DIM / THREADS; ++r) {   // 8
            const int i = r * THREADS + t;
            xs[i] = tb[i];
        }
        __syncthreads();                            // tile ready

        // ---- gather + unpack + packed FMA (regs + LDS only) ----
        const char* buf = (const char*)xs;
        f32x2 acc0 = {0.f,0.f}, acc1 = {0.f,0.f}, acc2 = {0.f,0.f}, acc3 = {0.f,0.f};
        #pragma unroll
        for (int g = 0; g < SAMPLE / 2; ++g) {
            const u32 pr = off[g];
            const uint4 q0 = *(const uint4*)(buf + (pr & 0xFFFFu));
            const uint4 q1 = *(const uint4*)(buf + (pr >> 16));
            const f32x2 w0 = {w[2*g],   w[2*g]};
            const f32x2 w1 = {w[2*g+1], w[2*g+1]};
            f32x2 v;
            v = (f32x2){__uint_as_float(q0.x << 16), __uint_as_float(q0.x & 0xFFFF0000u)};
            acc0 += v * w0;
            v = (f32x2){__uint_as_float(q0.y << 16), __uint_as_float(q0.y & 0xFFFF0000u)};
            acc1 += v * w0;
            v = (f32x2){__uint_as_float(q0.z << 16), __uint_as_float(q0.z & 0xFFFF0000u)};
            acc2 += v * w0;
            v = (f32x2){__uint_as_float(q0.w << 16), __uint_as_float(q0.w & 0xFFFF0000u)};
            acc3 += v * w0;
            v = (f32x2){__uint_as_float(q1.x << 16), __uint_as_float(q1.x & 0xFFFF0000u)};
            acc0 += v * w1;
            v = (f32x2){__uint_as_float(q1.y << 16), __uint_as_float(q1.y & 0xFFFF0000u)};
            acc1 += v * w1;
            v = (f32x2){__uint_as_float(q1.z << 16), __uint_as_float(q1.z & 0xFFFF0000u)};
            acc2 += v * w1;
            v = (f32x2){__uint_as_float(q1.w << 16), __uint_as_float(q1.w & 0xFFFF0000u)};
            acc3 += v * w1;
        }

        // ---- epilogue: activation, nontemporal dend store, soma reduce ----
        const float a[B_T] = {acc0.x, acc0.y, acc1.x, acc1.y,
                              acc2.x, acc2.y, acc3.x, acc3.y};
        float part[B_T];
        #pragma unroll
        for (int bb = 0; bb < B_T; ++bb) {
            const float pre = a[bb] + bias;
            const float act = (pre >= 0.f) ? pre : 0.1f * pre;
            __builtin_nontemporal_store(act, &dend_out[(size_t)(b0 + bb) * NDEND + d]);
            part[bb] = act * cwv;
        }
        #pragma unroll
        for (int m = 1; m < BRANCHES; m <<= 1) {
            #pragma unroll
            for (int bb = 0; bb < B_T; ++bb)
                part[bb] += __shfl_xor(part[bb], m);
        }
        if ((t & (BRANCHES - 1)) == 0) {
            #pragma unroll
            for (int bb = 0; bb < B_T; ++bb) {
                const float pre = part[bb] + sbi;
                soma_out[(size_t)(b0 + bb) * SOMA + n] = (pre >= 0.f) ? pre : 0.1f * pre;
            }
        }
    }
}

extern "C" void kernel_launch(void* const* d_in, const int* in_sizes, int n_in,
                              void* d_out, int out_size, void* d_ws, size_t ws_size,
                              hipStream_t stream) {
    const float* x     = (const float*)d_in[0];
    const int*   didx  = (const int*)  d_in[1];
    const float* sw    = (const float*)d_in[2];
    const float* sb    = (const float*)d_in[3];
    const float* cw    = (const float*)d_in[4];
    const float* somab = (const float*)d_in[5];

    float* soma_out = (float*)d_out;                     // [256][2048]
    float* dend_out = soma_out + (size_t)BATCH * SOMA;   // [256][32768]
    u32*   xP       = (u32*)d_ws;                        // 2 MiB bf16 LDS image

    dim3 pgrid(INPUT_DIM / TT, BATCH / TT);              // (64, 4)
    pack_kernel<<<pgrid, 256, 0, stream>>>(x, xP);

    // dc fastest-varying: XCD = dc%8; per-XCD working set = 2MB xP + 1MB idx/w
    dim3 grid(NDEND / THREADS, BATCH / (B_T * NBT));     // (64, 8)
    dendrite_kernel<<<grid, THREADS, 0, stream>>>((const uint4*)xP, didx, sw, sb,
                                                  cw, somab, soma_out, dend_out);
}

// Round 9
// 43.752 us; speedup vs baseline: 2.3921x; 1.0278x over previous
//
#include <hip/hip_runtime.h>

#define BATCH     256
#define INPUT_DIM 4096
#define SOMA      2048
#define BRANCHES  16
#define NDEND     32768
#define SAMPLE    32

#define THREADS   1024
#define B_T       8                       // batch rows per tile (8 bf16 per b128)
#define NBT       4                       // batch tiles per block -> 32 rows/block
#define TILE_B    (INPUT_DIM * 16)        // bytes per LDS buffer = 64 KiB

typedef unsigned int u32;
typedef float f32x2 __attribute__((ext_vector_type(2)));
typedef __attribute__((address_space(1))) const u32 gu32;
typedef __attribute__((address_space(3))) u32 lu32;

__device__ __forceinline__ void async_load16(const void* g, void* l) {
    __builtin_amdgcn_global_load_lds((const gu32*)g, (lu32*)l, 16, 0, 0);
}

__device__ __forceinline__ u32 bf16rne(float f) {   // round-to-nearest-even bf16
    u32 u = __float_as_uint(f);
    return (u + 0x7FFFu + ((u >> 16) & 1u)) >> 16;
}

// ---- pack x[256][4096] f32 -> xP[32 btile][4096 i][8 bb] bf16 (LDS image) ----
#define TT 64
__global__ __launch_bounds__(256)
void pack_kernel(const float* __restrict__ x, u32* __restrict__ xP)
{
    __shared__ float ts[TT * (TT + 1)];
    const int j  = threadIdx.x;
    const int tx = j & 63;
    const int ty = j >> 6;
    const int gi = blockIdx.x * TT;
    const int gb = blockIdx.y * TT;

    #pragma unroll
    for (int r = 0; r < 16; ++r) {
        const int b = ty + 4 * r;
        ts[tx * (TT + 1) + b] = x[(size_t)(gb + b) * INPUT_DIM + gi + tx];
    }
    __syncthreads();

    #pragma unroll
    for (int rep = 0; rep < 2; ++rep) {
        const int idx   = rep * 256 + j;
        const int i_loc = idx & 63;
        const int bg    = idx >> 6;
        const float* s  = &ts[i_loc * (TT + 1) + bg * 8];
        uint4 q;
        q.x = bf16rne(s[0]) | (bf16rne(s[1]) << 16);
        q.y = bf16rne(s[2]) | (bf16rne(s[3]) << 16);
        q.z = bf16rne(s[4]) | (bf16rne(s[5]) << 16);
        q.w = bf16rne(s[6]) | (bf16rne(s[7]) << 16);
        ((uint4*)xP)[(size_t)(gb / 8 + bg) * INPUT_DIM + gi + i_loc] = q;
    }
}

// ---------------- main fused kernel ----------------
__global__ __launch_bounds__(THREADS, 4)
void dendrite_kernel(const char* __restrict__ xP,   // [32][4096][8bb] bf16
                     const int*   __restrict__ didx,
                     const float* __restrict__ sw,
                     const float* __restrict__ sb,
                     const float* __restrict__ cw,
                     const float* __restrict__ somab,
                     float* __restrict__ soma_out,   // [BATCH][SOMA]
                     float* __restrict__ dend_out)   // [BATCH][NDEND]
{
    extern __shared__ char xs[];                    // 2 x 64 KiB double buffer

    const int t  = threadIdx.x;
    const int dc = blockIdx.x;   // dendrite chunk (32); XCD = (dc + 32*bs) % 8
    const int bs = blockIdx.y;   // batch super-tile (8)
    const int d  = dc * THREADS + t;                // this thread's dendrite, forever

    // ---- idx/w/bias/cable ONCE into registers ----
    uint  off[SAMPLE / 2];
    float w[SAMPLE];
    {
        const int4*   ip = (const int4*)  (didx + (size_t)d * SAMPLE);
        const float4* wp = (const float4*)(sw   + (size_t)d * SAMPLE);
        #pragma unroll
        for (int g = 0; g < SAMPLE / 4; ++g) {
            const int4   iv = ip[g];
            const float4 wv = wp[g];
            off[2*g]   = ((u32)iv.x << 4) | ((u32)iv.y << 20);  // byte off = i*16
            off[2*g+1] = ((u32)iv.z << 4) | ((u32)iv.w << 20);
            w[4*g] = wv.x; w[4*g+1] = wv.y; w[4*g+2] = wv.z; w[4*g+3] = wv.w;
        }
    }
    const float bias = sb[d];
    const float cwv  = cw[d];
    const int   n    = d >> 4;
    const float sbi  = somab[n];

    // ---- prologue: async stage tile 0 into buffer 0 (zero VGPR) ----
    {
        const char* tb = xP + (size_t)(bs * NBT) * TILE_B;
        #pragma unroll
        for (int r = 0; r < TILE_B / 16 / THREADS; ++r) {   // 4 per thread
            const int o = (r * THREADS + t) * 16;
            async_load16(tb + o, xs + o);
        }
    }

    for (int k = 0; k < NBT; ++k) {
        const int b0 = bs * (B_T * NBT) + k * B_T;

        // implicit s_waitcnt vmcnt(0) lgkmcnt(0) + barrier:
        //  - stage(k), issued one tile ago, has landed
        //  - all waves' gather reads of buf[(k+1)&1] (tile k-1) are complete
        __syncthreads();

        if (k + 1 < NBT) {                          // async stage(k+1), other buffer
            const char* tb = xP + (size_t)(bs * NBT + k + 1) * TILE_B;
            char* nbuf = xs + ((k + 1) & 1) * TILE_B;
            #pragma unroll
            for (int r = 0; r < TILE_B / 16 / THREADS; ++r) {
                const int o = (r * THREADS + t) * 16;
                async_load16(tb + o, nbuf + o);
            }
        }

        // ---- gather + unpack + packed FMA (regs + LDS only) ----
        const char* buf = xs + (k & 1) * TILE_B;
        f32x2 acc0 = {0.f,0.f}, acc1 = {0.f,0.f}, acc2 = {0.f,0.f}, acc3 = {0.f,0.f};
        #pragma unroll
        for (int g = 0; g < SAMPLE / 2; ++g) {
            const u32 pr = off[g];
            const uint4 q0 = *(const uint4*)(buf + (pr & 0xFFFFu));
            const uint4 q1 = *(const uint4*)(buf + (pr >> 16));
            const f32x2 w0 = {w[2*g],   w[2*g]};
            const f32x2 w1 = {w[2*g+1], w[2*g+1]};
            f32x2 v;
            v = (f32x2){__uint_as_float(q0.x << 16), __uint_as_float(q0.x & 0xFFFF0000u)};
            acc0 += v * w0;
            v = (f32x2){__uint_as_float(q0.y << 16), __uint_as_float(q0.y & 0xFFFF0000u)};
            acc1 += v * w0;
            v = (f32x2){__uint_as_float(q0.z << 16), __uint_as_float(q0.z & 0xFFFF0000u)};
            acc2 += v * w0;
            v = (f32x2){__uint_as_float(q0.w << 16), __uint_as_float(q0.w & 0xFFFF0000u)};
            acc3 += v * w0;
            v = (f32x2){__uint_as_float(q1.x << 16), __uint_as_float(q1.x & 0xFFFF0000u)};
            acc0 += v * w1;
            v = (f32x2){__uint_as_float(q1.y << 16), __uint_as_float(q1.y & 0xFFFF0000u)};
            acc1 += v * w1;
            v = (f32x2){__uint_as_float(q1.z << 16), __uint_as_float(q1.z & 0xFFFF0000u)};
            acc2 += v * w1;
            v = (f32x2){__uint_as_float(q1.w << 16), __uint_as_float(q1.w & 0xFFFF0000u)};
            acc3 += v * w1;
        }

        // ---- epilogue: activation, nontemporal dend store, soma reduce ----
        const float a[B_T] = {acc0.x, acc0.y, acc1.x, acc1.y,
                              acc2.x, acc2.y, acc3.x, acc3.y};
        float part[B_T];
        #pragma unroll
        for (int bb = 0; bb < B_T; ++bb) {
            const float pre = a[bb] + bias;
            const float act = (pre >= 0.f) ? pre : 0.1f * pre;
            __builtin_nontemporal_store(act, &dend_out[(size_t)(b0 + bb) * NDEND + d]);
            part[bb] = act * cwv;
        }
        #pragma unroll
        for (int m = 1; m < BRANCHES; m <<= 1) {
            #pragma unroll
            for (int bb = 0; bb < B_T; ++bb)
                part[bb] += __shfl_xor(part[bb], m);
        }
        if ((t & (BRANCHES - 1)) == 0) {
            #pragma unroll
            for (int bb = 0; bb < B_T; ++bb) {
                const float pre = part[bb] + sbi;
                soma_out[(size_t)(b0 + bb) * SOMA + n] = (pre >= 0.f) ? pre : 0.1f * pre;
            }
        }
    }
}

extern "C" void kernel_launch(void* const* d_in, const int* in_sizes, int n_in,
                              void* d_out, int out_size, void* d_ws, size_t ws_size,
                              hipStream_t stream) {
    const float* x     = (const float*)d_in[0];
    const int*   didx  = (const int*)  d_in[1];
    const float* sw    = (const float*)d_in[2];
    const float* sb    = (const float*)d_in[3];
    const float* cw    = (const float*)d_in[4];
    const float* somab = (const float*)d_in[5];

    float* soma_out = (float*)d_out;                     // [256][2048]
    float* dend_out = soma_out + (size_t)BATCH * SOMA;   // [256][32768]
    u32*   xP       = (u32*)d_ws;                        // 2 MiB bf16 LDS image

    static bool attr_set = false;                        // idempotent host config
    if (!attr_set) {
        hipFuncSetAttribute((const void*)dendrite_kernel,
                            hipFuncAttributeMaxDynamicSharedMemorySize, 2 * TILE_B);
        attr_set = true;
    }

    dim3 pgrid(INPUT_DIM / TT, BATCH / TT);              // (64, 4)
    pack_kernel<<<pgrid, 256, 0, stream>>>(x, xP);

    dim3 grid(NDEND / THREADS, BATCH / (B_T * NBT));     // (32, 8) = 256 blocks, 1/CU
    dendrite_kernel<<<grid, THREADS, 2 * TILE_B, stream>>>(
        (const char*)xP, didx, sw, sb, cw, somab, soma_out, dend_out);
}